// Round 5
// baseline (64.218 us; speedup 1.0000x reference)
//
#include <hip/hip_runtime.h>
#include <hip/hip_bf16.h>

typedef __attribute__((ext_vector_type(4))) float f32x4;
typedef __attribute__((ext_vector_type(8))) short s16x8;
typedef __attribute__((ext_vector_type(4))) short s16x4;

#define M_DIM 256
#define N_DIM 16384
#define K_DIM 2048
#define BN 64
#define BK 64
#define NKT 32            // K tiles of 64
#define TEMP_INV 20.0f
#define SPECIAL 5554
#define IGNORE_IDX 1023

__device__ __forceinline__ short f2bf(float x) {
  __hip_bfloat16 h = __float2bfloat16(x);
  return __builtin_bit_cast(short, h);
}

__device__ __forceinline__ void gload_lds16(const void* g, void* l) {
  __builtin_amdgcn_global_load_lds((const __attribute__((address_space(1))) void*)g,
                                   (__attribute__((address_space(3))) void*)l, 16, 0, 0);
}

// inputs f32 [256][2048] -> bf16 LDS-image. Tile kt (32 total) = 2048 chunks of
// 16B; chunk p = row*8 + s', s' = s ^ (row&7), holding A[row][kt*64 + s*8 ..+8].
// GEMM stages a tile linearly via global_load_lds; reads use the matching XOR.
__global__ __launch_bounds__(256) void convA(const float* __restrict__ A,
                                             short* __restrict__ Abf) {
  int fid = blockIdx.x * 256 + threadIdx.x;  // 0..65535
  int kt = fid >> 11;
  int p = fid & 2047;
  int row = p >> 3;
  int s = (p & 7) ^ (row & 7);
  const float* src = A + (size_t)row * K_DIM + kt * BK + s * 8;
  float4 lo = *(const float4*)src;
  float4 hi = *(const float4*)(src + 4);
  s16x8 h;
  h[0] = f2bf(lo.x); h[1] = f2bf(lo.y); h[2] = f2bf(lo.z); h[3] = f2bf(lo.w);
  h[4] = f2bf(hi.x); h[5] = f2bf(hi.y); h[6] = f2bf(hi.z); h[7] = f2bf(hi.w);
  *reinterpret_cast<s16x8*>(Abf + (size_t)fid * 8) = h;
}

// Fused GEMM + exp-rowsum + target capture. BM = 256 (full M): B read ONCE.
// 256 threads (4 waves, wave tile 64 rows x 64 cols), grid 256 = 1 block/CU.
__global__ __launch_bounds__(256, 1) void gemm_fused(
    const short* __restrict__ Abf, const float* __restrict__ B,
    const int* __restrict__ targets,
    float* __restrict__ partial,    // [256 bn][256 rows]
    float* __restrict__ targ) {     // [256]
  __shared__ __align__(16) short Al[2][M_DIM * BK];  // 2 x 32 KB
  __shared__ __align__(16) short Bl[2][BN * BK];     // 2 x 8 KB
  __shared__ int tcs[M_DIM];

  int bn = blockIdx.x;              // 0..255, one 64-col panel each
  int tid = threadIdx.x;
  int w = tid >> 6;                 // wave 0..3 -> rows w*64..+64
  int lane = tid & 63;
  int rl = lane & 15;
  int kq = lane >> 4;

  {
    int tt = targets[tid] - 1;
    if (tt == SPECIAL) tt = IGNORE_IDX;
    tcs[tid] = tt < 0 ? 0 : (tt > N_DIM - 1 ? N_DIM - 1 : tt);
  }

  // B staging: thread covers chunks c = j*256+tid ; row = c>>4, kc = c&15
  const float* bbase = B + ((size_t)bn * BN + (tid >> 4)) * K_DIM + (tid & 15) * 4;

  f32x4 acc[4][4];
#pragma unroll
  for (int m = 0; m < 4; ++m)
#pragma unroll
    for (int n = 0; n < 4; ++n) acc[m][n] = f32x4{0.f, 0.f, 0.f, 0.f};

  float4 R0[4], R1[4];  // two B-register sets, static indices only

#define ADMA(t, buf)                                                          \
  { _Pragma("unroll") for (int _j = 0; _j < 8; ++_j) {                        \
      int _c = _j * 256 + tid;                                                \
      gload_lds16(Abf + (((size_t)(t) * 2048 + _c) << 3),                     \
                  (char*)&Al[buf][0] + (size_t)_c * 16);                      \
  } }

#define BGLB(t, R)                                                            \
  { const float* _p = bbase + (size_t)(t) * BK;                               \
    _Pragma("unroll") for (int _j = 0; _j < 4; ++_j)                          \
        R[_j] = *(const float4*)(_p + (size_t)_j * 16 * K_DIM); }

#define CVTW(R, buf)                                                          \
  { int _kc = tid & 15; int _rr = tid >> 4;                                   \
    _Pragma("unroll") for (int _j = 0; _j < 4; ++_j) {                        \
      int _row = _j * 16 + _rr;                                               \
      int _off = _row * 64 + (((_kc >> 1) ^ (_row & 7)) << 3) + (_kc & 1) * 4;\
      s16x4 _h;                                                               \
      _h[0] = f2bf(R[_j].x); _h[1] = f2bf(R[_j].y);                           \
      _h[2] = f2bf(R[_j].z); _h[3] = f2bf(R[_j].w);                           \
      *reinterpret_cast<s16x4*>(&Bl[buf][0] + _off) = _h;                     \
    } }

#define COMPUTE(par)                                                          \
  { const short* _al = &Al[par][0]; const short* _bl = &Bl[par][0];           \
    _Pragma("unroll") for (int _kk = 0; _kk < 2; ++_kk) {                     \
      s16x8 _af[4], _bf[4];                                                   \
      int _sl = (_kk * 4 + kq) ^ (rl & 7);                                    \
      _Pragma("unroll") for (int _m = 0; _m < 4; ++_m) {                      \
        int _row = w * 64 + _m * 16 + rl;                                     \
        _af[_m] = *reinterpret_cast<const s16x8*>(_al + ((_row << 3) + _sl) * 8); \
      }                                                                       \
      _Pragma("unroll") for (int _n = 0; _n < 4; ++_n) {                      \
        int _row = _n * 16 + rl;                                              \
        _bf[_n] = *reinterpret_cast<const s16x8*>(_bl + ((_row << 3) + _sl) * 8); \
      }                                                                       \
      _Pragma("unroll") for (int _m = 0; _m < 4; ++_m)                        \
          _Pragma("unroll") for (int _n = 0; _n < 4; ++_n)                    \
              acc[_m][_n] = __builtin_amdgcn_mfma_f32_16x16x32_bf16(          \
                  _af[_m], _bf[_n], acc[_m][_n], 0, 0, 0);                    \
    } }

#define VMCNT(n) asm volatile("s_waitcnt vmcnt(" #n ")" ::: "memory")
#define BARRIER() asm volatile("s_waitcnt lgkmcnt(0)\n\ts_barrier" ::: "memory")

  // Prologue: A(0) dma, B(0)->R0, B(1)->R1, publish B(0); counted waits only.
  ADMA(0, 0);
  BGLB(0, R0);
  BGLB(1, R1);
  CVTW(R0, 0);      // compiler auto-waits R0 (vmcnt(4): B(1) stays in flight)
  VMCNT(4);         // own A(0) dma complete (B(1) 4 loads still flying)
  BARRIER();

  // Steady state, iters 0..29. Iter t: reads buf[t&1]; publishes B(t+1);
  // issues A-dma(t+1) and B-load(t+2). vmcnt(4) BEFORE barrier => each wave's
  // own A(t+1) dma is done when anyone crosses; B(t+2) never drained.
#pragma unroll
  for (int tb = 0; tb < 30; tb += 2) {
    {  // even iter t=tb: B(t+1) in R1, load B(t+2) into R0
      ADMA(tb + 1, 1);
      BGLB(tb + 2, R0);
      COMPUTE(0);
      CVTW(R1, 1);   // auto vmcnt(12)
      VMCNT(4);
      BARRIER();
    }
    {  // odd iter t=tb+1: B(t+1) in R0, load B(t+2) into R1
      ADMA(tb + 2, 0);
      BGLB(tb + 3, R1);
      COMPUTE(1);
      CVTW(R0, 0);
      VMCNT(4);
      BARRIER();
    }
  }
  // t=30: publish B(31) (in R1 after loop), drain A(31)
  {
    ADMA(31, 1);
    COMPUTE(0);
    CVTW(R1, 1);    // auto vmcnt(8)
    VMCNT(0);       // no younger loads remain: full drain of A(31)
    BARRIER();
  }
  // t=31: compute only
  COMPUTE(1);

  // ---- fused epilogue: wave owns the full 64-col panel for its rows ----
  int colbase = bn * BN + rl;
#pragma unroll
  for (int m = 0; m < 4; ++m) {
#pragma unroll
    for (int r = 0; r < 4; ++r) {
      int row = w * 64 + m * 16 + kq * 4 + r;
      int tc = tcs[row];
      float s = 0.f;
#pragma unroll
      for (int n = 0; n < 4; ++n) {
        float logit = acc[m][n][r] * TEMP_INV;
        if (colbase + n * 16 == tc) targ[row] = logit;
        s += __expf(logit);
      }
#pragma unroll
      for (int msk = 1; msk < 16; msk <<= 1) s += __shfl_xor(s, msk, 64);
      if (rl == 0) partial[(size_t)bn * M_DIM + row] = s;
    }
  }
#undef ADMA
#undef BGLB
#undef CVTW
#undef COMPUTE
#undef VMCNT
#undef BARRIER
}

__global__ __launch_bounds__(256) void finalize(
    const float* __restrict__ partial, const float* __restrict__ targ,
    const int* __restrict__ targets, float* __restrict__ out) {
  int r = threadIdx.x;  // 256 rows
  float s = 0.f;
  for (int j = 0; j < 256; ++j) s += partial[(size_t)j * M_DIM + r];
  int t = targets[r] - 1;
  if (t == SPECIAL) t = IGNORE_IDX;
  bool valid = (t >= 0) && (t != IGNORE_IDX);
  float nl = logf(s) - targ[r];
  float sv = valid ? nl : 0.0f;
  float cv = valid ? 1.0f : 0.0f;
#pragma unroll
  for (int m = 1; m < 64; m <<= 1) {
    sv += __shfl_xor(sv, m, 64);
    cv += __shfl_xor(cv, m, 64);
  }
  __shared__ float ss[4], cc[4];
  int wid = r >> 6, lane = r & 63;
  if (lane == 0) { ss[wid] = sv; cc[wid] = cv; }
  __syncthreads();
  if (r == 0) {
    float S = ss[0] + ss[1] + ss[2] + ss[3];
    float C = cc[0] + cc[1] + cc[2] + cc[3];
    out[0] = S / fmaxf(C, 1.0f);
  }
}

extern "C" void kernel_launch(void* const* d_in, const int* in_sizes, int n_in,
                              void* d_out, int out_size, void* d_ws, size_t ws_size,
                              hipStream_t stream) {
  const float* inputs   = (const float*)d_in[0];  // [256, 2048]
  const int*   targets  = (const int*)d_in[1];    // [256]
  const float* features = (const float*)d_in[2];  // [16384, 2048]
  float* out = (float*)d_out;

  short* Abf     = (short*)d_ws;                        // 1 MB bf16 image
  float* partial = (float*)((char*)d_ws + (1 << 20));   // [256][256] f32 = 256 KB
  float* targ    = partial + 256 * M_DIM;               // [256] f32

  convA<<<dim3(256), dim3(256), 0, stream>>>(inputs, Abf);
  gemm_fused<<<dim3(256), dim3(256), 0, stream>>>(Abf, features, targets, partial, targ);
  finalize<<<dim3(1), dim3(256), 0, stream>>>(partial, targ, targets, out);
}

// Round 6
// 57.620 us; speedup vs baseline: 1.1145x; 1.1145x over previous
//
#include <hip/hip_runtime.h>
#include <hip/hip_bf16.h>

typedef __attribute__((ext_vector_type(4))) float f32x4;
typedef __attribute__((ext_vector_type(8))) short s16x8;
typedef __attribute__((ext_vector_type(4))) short s16x4;

#define M_DIM 256
#define N_DIM 16384
#define K_DIM 2048
#define BN 64
#define BK 64
#define NKT 32            // K tiles of 64
#define TEMP_INV 20.0f
#define SPECIAL 5554
#define IGNORE_IDX 1023

__device__ __forceinline__ short f2bf(float x) {
  __hip_bfloat16 h = __float2bfloat16(x);
  return __builtin_bit_cast(short, h);
}

__device__ __forceinline__ void gload_lds16(const void* g, void* l) {
  __builtin_amdgcn_global_load_lds((const __attribute__((address_space(1))) void*)g,
                                   (__attribute__((address_space(3))) void*)l, 16, 0, 0);
}

// inputs f32 [256][2048] -> bf16 LDS-image. Tile kt (32 total) = 2048 chunks of
// 16B; chunk p = row*8 + s', s' = s ^ (row&7), holding A[row][kt*64 + s*8 ..+8].
// GEMM stages a tile linearly via global_load_lds; reads use the matching XOR.
__global__ __launch_bounds__(256) void convA(const float* __restrict__ A,
                                             short* __restrict__ Abf) {
  int fid = blockIdx.x * 256 + threadIdx.x;  // 0..65535
  int kt = fid >> 11;
  int p = fid & 2047;
  int row = p >> 3;
  int s = (p & 7) ^ (row & 7);
  const float* src = A + (size_t)row * K_DIM + kt * BK + s * 8;
  float4 lo = *(const float4*)src;
  float4 hi = *(const float4*)(src + 4);
  s16x8 h;
  h[0] = f2bf(lo.x); h[1] = f2bf(lo.y); h[2] = f2bf(lo.z); h[3] = f2bf(lo.w);
  h[4] = f2bf(hi.x); h[5] = f2bf(hi.y); h[6] = f2bf(hi.z); h[7] = f2bf(hi.w);
  *reinterpret_cast<s16x8*>(Abf + (size_t)fid * 8) = h;
}

// Fused GEMM + exp-rowsum + target capture. BM = 256 (full M): B read ONCE.
// 512 threads = 8 waves (2/SIMD for latency hiding), wave tile 64 rows x 32 cols.
__global__ __launch_bounds__(512, 2) void gemm_fused(
    const short* __restrict__ Abf, const float* __restrict__ B,
    const int* __restrict__ targets,
    float* __restrict__ partial,    // [256 bn][256 rows]
    float* __restrict__ targ) {     // [256]
  __shared__ __align__(16) short Al[2][M_DIM * BK];  // 2 x 32 KB (bf16)
  __shared__ __align__(16) short Bl[2][BN * BK];     // 2 x 8 KB (bf16)
  __shared__ int tcs[M_DIM];
  __shared__ float rsum[M_DIM][2];

  int bn = blockIdx.x;              // 0..255, one 64-col panel each
  int tid = threadIdx.x;
  int wave = tid >> 6;
  int lane = tid & 63;
  int rl = lane & 15;
  int kq = lane >> 4;
  int wm = wave >> 1;               // 0..3 -> rows wm*64..+63
  int wn = wave & 1;                // 0..1 -> cols wn*32..+31

  if (tid < M_DIM) {
    int tt = targets[tid] - 1;
    if (tt == SPECIAL) tt = IGNORE_IDX;
    tcs[tid] = tt < 0 ? 0 : (tt > N_DIM - 1 ? N_DIM - 1 : tt);
  }

  // B staging: thread covers f32 16B-chunks c = tid and c = tid+512;
  // row = c>>4 (0..63), kc = c&15 (4 floats at k = kc*4).
  const float* bbase = B + ((size_t)bn * BN + (tid >> 4)) * K_DIM + (tid & 15) * 4;

  f32x4 acc[4][2];
#pragma unroll
  for (int m = 0; m < 4; ++m)
#pragma unroll
    for (int n = 0; n < 2; ++n) acc[m][n] = f32x4{0.f, 0.f, 0.f, 0.f};

  float4 R0[2], R1[2];  // two B-register sets, static indices only

#define ADMA(t, buf)                                                          \
  { _Pragma("unroll") for (int _j = 0; _j < 4; ++_j) {                        \
      int _c = _j * 512 + tid;                                                \
      gload_lds16(Abf + (((size_t)(t) * 2048 + _c) << 3),                     \
                  (char*)&Al[buf][0] + (size_t)_c * 16);                      \
  } }

#define BGLB(t, R)                                                            \
  { const float* _p = bbase + (size_t)(t) * BK;                               \
    R[0] = *(const float4*)_p;                                                \
    R[1] = *(const float4*)(_p + (size_t)32 * K_DIM); }

#define CVTW(R, buf)                                                          \
  { int _kc = tid & 15; int _r0 = tid >> 4;                                   \
    _Pragma("unroll") for (int _j = 0; _j < 2; ++_j) {                        \
      int _row = _r0 + _j * 32;                                               \
      int _off = _row * 64 + (((_kc >> 1) ^ (_row & 7)) << 3) + (_kc & 1) * 4;\
      s16x4 _h;                                                               \
      _h[0] = f2bf(R[_j].x); _h[1] = f2bf(R[_j].y);                           \
      _h[2] = f2bf(R[_j].z); _h[3] = f2bf(R[_j].w);                           \
      *reinterpret_cast<s16x4*>(&Bl[buf][0] + _off) = _h;                     \
    } }

#define COMPUTE(par)                                                          \
  { const short* _al = &Al[par][0]; const short* _bl = &Bl[par][0];           \
    _Pragma("unroll") for (int _kk = 0; _kk < 2; ++_kk) {                     \
      s16x8 _af[4], _bf[2];                                                   \
      int _s0 = _kk * 4 + kq;                                                 \
      _Pragma("unroll") for (int _m = 0; _m < 4; ++_m) {                      \
        int _row = wm * 64 + _m * 16 + rl;                                    \
        _af[_m] = *reinterpret_cast<const s16x8*>(                            \
            _al + ((_row << 3) + (_s0 ^ (_row & 7))) * 8);                    \
      }                                                                       \
      _Pragma("unroll") for (int _n = 0; _n < 2; ++_n) {                      \
        int _row = wn * 32 + _n * 16 + rl;                                    \
        _bf[_n] = *reinterpret_cast<const s16x8*>(                            \
            _bl + ((_row << 3) + (_s0 ^ (_row & 7))) * 8);                    \
      }                                                                       \
      _Pragma("unroll") for (int _m = 0; _m < 4; ++_m)                        \
          _Pragma("unroll") for (int _n = 0; _n < 2; ++_n)                    \
              acc[_m][_n] = __builtin_amdgcn_mfma_f32_16x16x32_bf16(          \
                  _af[_m], _bf[_n], acc[_m][_n], 0, 0, 0);                    \
    } }

#define VMCNT(n) asm volatile("s_waitcnt vmcnt(" #n ")" ::: "memory")
#define BARRIER() asm volatile("s_waitcnt lgkmcnt(0)\n\ts_barrier" ::: "memory")

  // Prologue: A(0) dma, B(0)->R0, B(1)->R1, publish B(0). Counted waits only.
  ADMA(0, 0);
  BGLB(0, R0);
  BGLB(1, R1);
  CVTW(R0, 0);      // compiler auto-waits B(0) (vmcnt(2): B(1) stays in flight)
  VMCNT(2);         // own A(0) dma complete; B(1)'s 2 loads still flying
  BARRIER();

  // Steady state. Iter t: reads buf[t&1]; publishes B(t+1); issues A-dma(t+1)
  // and B(t+2). VMCNT(2) before the barrier: own A(t+1) dma done at publish
  // time, B(t+2) never drained. One barrier per K-tile.
#pragma unroll
  for (int tb = 0; tb < 30; tb += 2) {
    {  // even iter: B(t+1) in R1, load B(t+2) into R0
      ADMA(tb + 1, 1);
      BGLB(tb + 2, R0);
      COMPUTE(0);
      CVTW(R1, 1);   // auto vmcnt(6)
      VMCNT(2);
      BARRIER();
    }
    {  // odd iter: B(t+1) in R0, load B(t+2) into R1
      ADMA(tb + 2, 0);
      BGLB(tb + 3, R1);
      COMPUTE(1);
      CVTW(R0, 0);
      VMCNT(2);
      BARRIER();
    }
  }
  // t=30: publish B(31) (in R1), drain A(31)
  {
    ADMA(31, 1);
    COMPUTE(0);
    CVTW(R1, 1);
    VMCNT(0);       // no younger loads remain
    BARRIER();
  }
  // t=31: compute only
  COMPUTE(1);

  // ---- fused epilogue ----
  int colbase = bn * BN + wn * 32 + rl;
#pragma unroll
  for (int m = 0; m < 4; ++m) {
#pragma unroll
    for (int r = 0; r < 4; ++r) {
      int row = wm * 64 + m * 16 + kq * 4 + r;
      int tc = tcs[row];
      float s = 0.f;
#pragma unroll
      for (int n = 0; n < 2; ++n) {
        float logit = acc[m][n][r] * TEMP_INV;
        if (colbase + n * 16 == tc) targ[row] = logit;
        s += __expf(logit);
      }
#pragma unroll
      for (int msk = 1; msk < 16; msk <<= 1) s += __shfl_xor(s, msk, 64);
      if (rl == 0) rsum[row][wn] = s;
    }
  }
  __syncthreads();
  if (tid < M_DIM) {
    partial[(size_t)bn * M_DIM + tid] = rsum[tid][0] + rsum[tid][1];
  }
#undef ADMA
#undef BGLB
#undef CVTW
#undef COMPUTE
#undef VMCNT
#undef BARRIER
}

__global__ __launch_bounds__(256) void finalize(
    const float* __restrict__ partial, const float* __restrict__ targ,
    const int* __restrict__ targets, float* __restrict__ out) {
  int r = threadIdx.x;  // 256 rows
  float s = 0.f;
  for (int j = 0; j < 256; ++j) s += partial[(size_t)j * M_DIM + r];
  int t = targets[r] - 1;
  if (t == SPECIAL) t = IGNORE_IDX;
  bool valid = (t >= 0) && (t != IGNORE_IDX);
  float nl = logf(s) - targ[r];
  float sv = valid ? nl : 0.0f;
  float cv = valid ? 1.0f : 0.0f;
#pragma unroll
  for (int m = 1; m < 64; m <<= 1) {
    sv += __shfl_xor(sv, m, 64);
    cv += __shfl_xor(cv, m, 64);
  }
  __shared__ float ss[4], cc[4];
  int wid = r >> 6, lane = r & 63;
  if (lane == 0) { ss[wid] = sv; cc[wid] = cv; }
  __syncthreads();
  if (r == 0) {
    float S = ss[0] + ss[1] + ss[2] + ss[3];
    float C = cc[0] + cc[1] + cc[2] + cc[3];
    out[0] = S / fmaxf(C, 1.0f);
  }
}

extern "C" void kernel_launch(void* const* d_in, const int* in_sizes, int n_in,
                              void* d_out, int out_size, void* d_ws, size_t ws_size,
                              hipStream_t stream) {
  const float* inputs   = (const float*)d_in[0];  // [256, 2048]
  const int*   targets  = (const int*)d_in[1];    // [256]
  const float* features = (const float*)d_in[2];  // [16384, 2048]
  float* out = (float*)d_out;

  short* Abf     = (short*)d_ws;                        // 1 MB bf16 image
  float* partial = (float*)((char*)d_ws + (1 << 20));   // [256][256] f32 = 256 KB
  float* targ    = partial + 256 * M_DIM;               // [256] f32

  convA<<<dim3(256), dim3(256), 0, stream>>>(inputs, Abf);
  gemm_fused<<<dim3(256), dim3(512), 0, stream>>>(Abf, features, targets, partial, targ);
  finalize<<<dim3(1), dim3(256), 0, stream>>>(partial, targ, targets, out);
}

// Round 7
// 50.368 us; speedup vs baseline: 1.2750x; 1.1440x over previous
//
#include <hip/hip_runtime.h>
#include <hip/hip_bf16.h>

typedef __attribute__((ext_vector_type(4))) float f32x4;
typedef __attribute__((ext_vector_type(8))) short s16x8;
typedef __attribute__((ext_vector_type(4))) short s16x4;

#define M_DIM 256
#define N_DIM 16384
#define K_DIM 2048
#define BM 128
#define BN 64
#define BK 64
#define NKT 32            // K tiles of 64
#define TEMP_INV 20.0f
#define SPECIAL 5554
#define IGNORE_IDX 1023

__device__ __forceinline__ short f2bf(float x) {
  __hip_bfloat16 h = __float2bfloat16(x);
  return __builtin_bit_cast(short, h);
}

__device__ __forceinline__ void gload_lds16(const void* g, void* l) {
  __builtin_amdgcn_global_load_lds((const __attribute__((address_space(1))) void*)g,
                                   (__attribute__((address_space(3))) void*)l, 16, 0, 0);
}

// inputs f32 [256][2048] -> bf16 LDS-image. Tile T = bm*32 + kt holds 1024
// 16B-chunks: chunk p = row*8 + s', s' = s ^ (row&7), covering
// A[bm*128 + row][kt*64 + s*8 .. +8]. GEMM stages linearly via global_load_lds;
// frag reads apply the matching XOR (rule 21: swizzle both sides).
__global__ __launch_bounds__(256) void convA(const float* __restrict__ A,
                                             short* __restrict__ Abf) {
  int fid = blockIdx.x * 256 + threadIdx.x;  // 0..65535
  int T = fid >> 10;         // bm*32 + kt
  int p = fid & 1023;
  int row = p >> 3;          // 0..127
  int s = (p & 7) ^ (row & 7);
  int bm = T >> 5;
  int kt = T & 31;
  const float* src = A + (size_t)(bm * BM + row) * K_DIM + kt * BK + s * 8;
  float4 lo = *(const float4*)src;
  float4 hi = *(const float4*)(src + 4);
  s16x8 h;
  h[0] = f2bf(lo.x); h[1] = f2bf(lo.y); h[2] = f2bf(lo.z); h[3] = f2bf(lo.w);
  h[4] = f2bf(hi.x); h[5] = f2bf(hi.y); h[6] = f2bf(hi.z); h[7] = f2bf(hi.w);
  *reinterpret_cast<s16x8*>(Abf + (size_t)fid * 8) = h;
}

// Fused GEMM + exp-rowsum + target capture.
// 256 threads = 4 waves (wave tile 64x32), grid 512 = 2 independent blocks/CU.
// Counted-vmcnt pipeline (identical wait scheme to the validated R6 kernel).
__global__ __launch_bounds__(256, 2) void gemm_fused(
    const short* __restrict__ Abf, const float* __restrict__ B,
    const int* __restrict__ targets,
    float* __restrict__ partial,    // [256 bn][256 rows]
    float* __restrict__ targ) {     // [256]
  __shared__ __align__(16) short Al[2][BM * BK];   // 2 x 16 KB (bf16)
  __shared__ __align__(16) short Bl[2][BN * BK];   // 2 x 8 KB (bf16)
  __shared__ int tcs[BM];
  __shared__ float rsum[BM][2];

  // XCD-bijective swizzle (512 % 8 == 0): consecutive lbid pairs = the two
  // bm-halves of one bn panel -> same XCD, B HBM-fetched once, L2-served twice.
  int bid = blockIdx.x;
  int lbid = (bid & 7) * 64 + (bid >> 3);
  int bm = lbid & 1;    // 0..1
  int bn = lbid >> 1;   // 0..255

  int tid = threadIdx.x;
  int wave = tid >> 6;
  int lane = tid & 63;
  int rl = lane & 15;
  int kq = lane >> 4;
  int wm = wave >> 1;   // 0..1 -> rows wm*64..+63
  int wn = wave & 1;    // 0..1 -> cols wn*32..+31

  if (tid < BM) {
    int tt = targets[bm * BM + tid] - 1;
    if (tt == SPECIAL) tt = IGNORE_IDX;
    tcs[tid] = tt < 0 ? 0 : (tt > N_DIM - 1 ? N_DIM - 1 : tt);
  }

  // B staging: chunks c = j*256 + tid (j=0..3); row = c>>4 (0..63), kc = c&15.
  const float* bbase = B + ((size_t)bn * BN + (tid >> 4)) * K_DIM + (tid & 15) * 4;

  f32x4 acc[4][2];
#pragma unroll
  for (int m = 0; m < 4; ++m)
#pragma unroll
    for (int n = 0; n < 2; ++n) acc[m][n] = f32x4{0.f, 0.f, 0.f, 0.f};

  float4 S0[4], S1[4];  // two B-register sets, static indices only

#define ADMA(t, buf)                                                          \
  { _Pragma("unroll") for (int _j = 0; _j < 4; ++_j) {                        \
      int _c = _j * 256 + tid;                                                \
      gload_lds16(Abf + (((size_t)(bm * 32 + (t)) * 1024 + _c) << 3),         \
                  (char*)&Al[buf][0] + (size_t)_c * 16);                      \
  } }

#define BGLB(t, R)                                                            \
  { const float* _p = bbase + (size_t)(t) * BK;                               \
    _Pragma("unroll") for (int _j = 0; _j < 4; ++_j)                          \
        R[_j] = *(const float4*)(_p + (size_t)_j * 16 * K_DIM); }

#define CVTW(R, buf)                                                          \
  { int _kc = tid & 15; int _r0 = tid >> 4;                                   \
    _Pragma("unroll") for (int _j = 0; _j < 4; ++_j) {                        \
      int _row = _r0 + _j * 16;                                               \
      int _off = _row * 64 + (((_kc >> 1) ^ (_row & 7)) << 3) + (_kc & 1) * 4;\
      s16x4 _h;                                                               \
      _h[0] = f2bf(R[_j].x); _h[1] = f2bf(R[_j].y);                           \
      _h[2] = f2bf(R[_j].z); _h[3] = f2bf(R[_j].w);                           \
      *reinterpret_cast<s16x4*>(&Bl[buf][0] + _off) = _h;                     \
    } }

#define COMPUTE(par)                                                          \
  { const short* _al = &Al[par][0]; const short* _bl = &Bl[par][0];           \
    _Pragma("unroll") for (int _kk = 0; _kk < 2; ++_kk) {                     \
      s16x8 _af[4], _bf[2];                                                   \
      int _s0 = _kk * 4 + kq;                                                 \
      _Pragma("unroll") for (int _m = 0; _m < 4; ++_m) {                      \
        int _row = wm * 64 + _m * 16 + rl;                                    \
        _af[_m] = *reinterpret_cast<const s16x8*>(                            \
            _al + ((_row << 3) + (_s0 ^ (_row & 7))) * 8);                    \
      }                                                                       \
      _Pragma("unroll") for (int _n = 0; _n < 2; ++_n) {                      \
        int _row = wn * 32 + _n * 16 + rl;                                    \
        _bf[_n] = *reinterpret_cast<const s16x8*>(                            \
            _bl + ((_row << 3) + (_s0 ^ (_row & 7))) * 8);                    \
      }                                                                       \
      _Pragma("unroll") for (int _m = 0; _m < 4; ++_m)                        \
          _Pragma("unroll") for (int _n = 0; _n < 2; ++_n)                    \
              acc[_m][_n] = __builtin_amdgcn_mfma_f32_16x16x32_bf16(          \
                  _af[_m], _bf[_n], acc[_m][_n], 0, 0, 0);                    \
    } }

#define VMCNT(n) asm volatile("s_waitcnt vmcnt(" #n ")" ::: "memory")
#define BARRIER() asm volatile("s_waitcnt lgkmcnt(0)\n\ts_barrier" ::: "memory")

  // Prologue: A(0) dma, B(0)->S0, B(1)->S1, publish B(0). Counted waits only.
  ADMA(0, 0);
  BGLB(0, S0);
  BGLB(1, S1);
  CVTW(S0, 0);      // auto-wait covers B(0) (and queue-older A(0) dma)
  VMCNT(4);         // own A(0) dma complete; B(1)'s 4 loads still flying
  BARRIER();

  // Steady state. Iter t: reads buf[t&1]; publishes B(t+1); issues A-dma(t+1)
  // and B(t+2). VMCNT(4) before the barrier: own A(t+1) dma done at publish
  // time, B(t+2) never drained. One barrier per K-tile.
#pragma unroll
  for (int tb = 0; tb < 30; tb += 2) {
    {  // even iter: B(t+1) in S1, load B(t+2) into S0
      ADMA(tb + 1, 1);
      BGLB(tb + 2, S0);
      COMPUTE(0);
      CVTW(S1, 1);   // auto counted wait (A(t+1)+B(t+2) stay in flight)
      VMCNT(4);
      BARRIER();
    }
    {  // odd iter: B(t+1) in S0, load B(t+2) into S1
      ADMA(tb + 2, 0);
      BGLB(tb + 3, S1);
      COMPUTE(1);
      CVTW(S0, 0);
      VMCNT(4);
      BARRIER();
    }
  }
  // t=30: publish B(31) (in S1), drain A(31)
  {
    ADMA(31, 1);
    COMPUTE(0);
    CVTW(S1, 1);
    VMCNT(0);       // no younger loads remain
    BARRIER();
  }
  // t=31: compute only
  COMPUTE(1);

  // ---- fused epilogue ----
  int colbase = bn * BN + wn * 32 + rl;
#pragma unroll
  for (int m = 0; m < 4; ++m) {
#pragma unroll
    for (int r = 0; r < 4; ++r) {
      int rloc = wm * 64 + m * 16 + kq * 4 + r;   // 0..127
      int tc = tcs[rloc];
      float s = 0.f;
#pragma unroll
      for (int n = 0; n < 2; ++n) {
        float logit = acc[m][n][r] * TEMP_INV;
        if (colbase + n * 16 == tc) targ[bm * BM + rloc] = logit;
        s += __expf(logit);
      }
#pragma unroll
      for (int msk = 1; msk < 16; msk <<= 1) s += __shfl_xor(s, msk, 64);
      if (rl == 0) rsum[rloc][wn] = s;
    }
  }
  __syncthreads();
  if (tid < BM) {
    partial[(size_t)bn * M_DIM + bm * BM + tid] = rsum[tid][0] + rsum[tid][1];
  }
#undef ADMA
#undef BGLB
#undef CVTW
#undef COMPUTE
#undef VMCNT
#undef BARRIER
}

__global__ __launch_bounds__(256) void finalize(
    const float* __restrict__ partial, const float* __restrict__ targ,
    const int* __restrict__ targets, float* __restrict__ out) {
  int r = threadIdx.x;  // 256 rows
  float s = 0.f;
  for (int j = 0; j < 256; ++j) s += partial[(size_t)j * M_DIM + r];
  int t = targets[r] - 1;
  if (t == SPECIAL) t = IGNORE_IDX;
  bool valid = (t >= 0) && (t != IGNORE_IDX);
  float nl = logf(s) - targ[r];
  float sv = valid ? nl : 0.0f;
  float cv = valid ? 1.0f : 0.0f;
#pragma unroll
  for (int m = 1; m < 64; m <<= 1) {
    sv += __shfl_xor(sv, m, 64);
    cv += __shfl_xor(cv, m, 64);
  }
  __shared__ float ss[4], cc[4];
  int wid = r >> 6, lane = r & 63;
  if (lane == 0) { ss[wid] = sv; cc[wid] = cv; }
  __syncthreads();
  if (r == 0) {
    float S = ss[0] + ss[1] + ss[2] + ss[3];
    float C = cc[0] + cc[1] + cc[2] + cc[3];
    out[0] = S / fmaxf(C, 1.0f);
  }
}

extern "C" void kernel_launch(void* const* d_in, const int* in_sizes, int n_in,
                              void* d_out, int out_size, void* d_ws, size_t ws_size,
                              hipStream_t stream) {
  const float* inputs   = (const float*)d_in[0];  // [256, 2048]
  const int*   targets  = (const int*)d_in[1];    // [256]
  const float* features = (const float*)d_in[2];  // [16384, 2048]
  float* out = (float*)d_out;

  short* Abf     = (short*)d_ws;                        // 1 MB bf16 image
  float* partial = (float*)((char*)d_ws + (1 << 20));   // [256][256] f32 = 256 KB
  float* targ    = partial + 256 * M_DIM;               // [256] f32

  convA<<<dim3(256), dim3(256), 0, stream>>>(inputs, Abf);
  gemm_fused<<<dim3(512), dim3(256), 0, stream>>>(Abf, features, targets, partial, targ);
  finalize<<<dim3(1), dim3(256), 0, stream>>>(partial, targ, targets, out);
}

// Round 8
// 45.365 us; speedup vs baseline: 1.4156x; 1.1103x over previous
//
#include <hip/hip_runtime.h>
#include <hip/hip_bf16.h>

typedef __attribute__((ext_vector_type(4))) float f32x4;
typedef __attribute__((ext_vector_type(8))) short s16x8;

#define M_DIM 256
#define N_DIM 16384
#define K_DIM 2048
#define BM 128
#define BN 128
#define BK 32
#define LDS_PITCH 40          // 32 + 8 bf16 pad (R2-proven layout)
#define NKT (K_DIM / BK)      // 64
#define TEMP_INV 20.0f
#define SPECIAL 5554
#define IGNORE_IDX 1023

__device__ __forceinline__ short f2bf(float x) {
  __hip_bfloat16 h = __float2bfloat16(x);
  return __builtin_bit_cast(short, h);
}

__device__ __forceinline__ void cvt_store(short* dst, const float4& f0, const float4& f1) {
  s16x8 h;
  h[0] = f2bf(f0.x); h[1] = f2bf(f0.y); h[2] = f2bf(f0.z); h[3] = f2bf(f0.w);
  h[4] = f2bf(f1.x); h[5] = f2bf(f1.y); h[6] = f2bf(f1.z); h[7] = f2bf(f1.w);
  *reinterpret_cast<s16x8*>(dst) = h;
}

// inputs f32 [256][2048] -> bf16 A-image matched to the gemm staging threads:
// chunk fid = (bm*64 + kt)*512 + c, c = tid; holds A[bm*128 + (c>>2)]
// [kt*32 + (c&3)*8 .. +8] as 8 bf16 (16 B). gemm thread tid loads chunk tid.
__global__ __launch_bounds__(256) void convA(const float* __restrict__ A,
                                             short* __restrict__ Abf) {
  int fid = blockIdx.x * 256 + threadIdx.x;  // 0..65535
  int bm = fid >> 15;          // 0..1
  int kt = (fid >> 9) & 63;    // 0..63
  int c = fid & 511;
  int row = c >> 2;            // 0..127
  int squad = c & 3;
  const float* src = A + (size_t)(bm * BM + row) * K_DIM + kt * BK + squad * 8;
  float4 lo = *(const float4*)src;
  float4 hi = *(const float4*)(src + 4);
  s16x8 h;
  h[0] = f2bf(lo.x); h[1] = f2bf(lo.y); h[2] = f2bf(lo.z); h[3] = f2bf(lo.w);
  h[4] = f2bf(hi.x); h[5] = f2bf(hi.y); h[6] = f2bf(hi.z); h[7] = f2bf(hi.w);
  *reinterpret_cast<s16x8*>(Abf + (size_t)fid * 8) = h;
}

// R2 structure verbatim (compiler-scheduled, plain __syncthreads, reg-prefetch
// across barriers) with A staged from the bf16 image (1 load + 1 ds_write,
// no cvt) instead of f32+convert. B path identical to R2.
__global__ __launch_bounds__(512, 1) void gemm_fused(
    const short* __restrict__ Abf, const float* __restrict__ B,
    const int* __restrict__ targets,
    float* __restrict__ partial,   // [128 bn][256 row]
    float* __restrict__ targ) {    // [256]
  __shared__ __align__(16) short As[2][BM * LDS_PITCH];
  __shared__ __align__(16) short Bs[2][BN * LDS_PITCH];
  __shared__ int tcs[BM];
  __shared__ float rsum[BM][4];

  // XCD-bijective swizzle (256 % 8 == 0): consecutive lbid (2 bm x same bn)
  // share one XCD's L2 for the B panel.
  int bid = blockIdx.x;
  int lbid = (bid & 7) * 32 + (bid >> 3);
  int bm = lbid & 1;        // 0..1
  int bn = lbid >> 1;       // 0..127

  int tid = threadIdx.x;
  int wave = tid >> 6;
  int lane = tid & 63;
  int wm = wave >> 2;       // 0..1  -> 64 rows
  int wn = wave & 3;        // 0..3  -> 32 cols

  if (tid < BM) {
    int tt = targets[bm * BM + tid] - 1;
    if (tt == SPECIAL) tt = IGNORE_IDX;
    tcs[tid] = tt < 0 ? 0 : (tt > N_DIM - 1 ? N_DIM - 1 : tt);
  }

  // staging thread map (R2): srow = tid>>2, squad = tid&3
  int srow = tid >> 2;
  int squad = tid & 3;
  const s16x8* aImg = (const s16x8*)Abf + (size_t)bm * 64 * 512 + tid;  // +kt*512
  const float* bG = B + (size_t)(bn * BN + srow) * K_DIM + squad * 8;
  int swoff = srow * LDS_PITCH + squad * 8;

  f32x4 acc[4][2];
#pragma unroll
  for (int mi = 0; mi < 4; ++mi)
#pragma unroll
    for (int ni = 0; ni < 2; ++ni)
      acc[mi][ni] = f32x4{0.f, 0.f, 0.f, 0.f};

  s16x8 rA[2];          // A chunk per reg set (bf16, ready to ds_write)
  float4 rB[2][2];      // B f32 per reg set; static indices after unroll

  // prologue: tile0 -> set0 -> buf0 ; issue tile1 -> set1
  rA[0] = aImg[0];
  rB[0][0] = *(const float4*)(bG);      rB[0][1] = *(const float4*)(bG + 4);
  *reinterpret_cast<s16x8*>(&As[0][swoff]) = rA[0];
  cvt_store(&Bs[0][swoff], rB[0][0], rB[0][1]);
  rA[1] = aImg[512];
  rB[1][0] = *(const float4*)(bG + BK); rB[1][1] = *(const float4*)(bG + BK + 4);
  __syncthreads();

  int arow0 = (wm * 64 + (lane & 15)) * LDS_PITCH + (lane >> 4) * 8;
  int brow0 = (wn * 32 + (lane & 15)) * LDS_PITCH + (lane >> 4) * 8;

  for (int ktb = 0; ktb < NKT; ktb += 2) {
#pragma unroll
    for (int u = 0; u < 2; ++u) {       // u == kt & 1 (static after unroll)
      int kt = ktb + u;
      const short* asb = &As[u][0];
      const short* bsb = &Bs[u][0];
      s16x8 af[4], bfr[2];
#pragma unroll
      for (int mi = 0; mi < 4; ++mi)
        af[mi] = *reinterpret_cast<const s16x8*>(asb + arow0 + mi * 16 * LDS_PITCH);
#pragma unroll
      for (int ni = 0; ni < 2; ++ni)
        bfr[ni] = *reinterpret_cast<const s16x8*>(bsb + brow0 + ni * 16 * LDS_PITCH);
#pragma unroll
      for (int mi = 0; mi < 4; ++mi)
#pragma unroll
        for (int ni = 0; ni < 2; ++ni)
          acc[mi][ni] = __builtin_amdgcn_mfma_f32_16x16x32_bf16(
              af[mi], bfr[ni], acc[mi][ni], 0, 0, 0);

      if (kt + 1 < NKT) {
        // write tile kt+1 (reg set u^1) into the other LDS buffer
        *reinterpret_cast<s16x8*>(&As[u ^ 1][swoff]) = rA[u ^ 1];
        cvt_store(&Bs[u ^ 1][swoff], rB[u ^ 1][0], rB[u ^ 1][1]);
        if (kt + 2 < NKT) {
          rA[u] = aImg[(size_t)(kt + 2) * 512];
          const float* bp = bG + (size_t)(kt + 2) * BK;
          rB[u][0] = *(const float4*)bp;  rB[u][1] = *(const float4*)(bp + 4);
        }
        __syncthreads();
      }
    }
  }

  // ---- fused epilogue (R2): exp + per-row reduce + target capture ----
  int g = lane >> 4;              // 0..3
  int cl = lane & 15;             // 0..15
  int gcol_base = bn * BN + wn * 32 + cl;
#pragma unroll
  for (int mi = 0; mi < 4; ++mi) {
#pragma unroll
    for (int r = 0; r < 4; ++r) {
      int rl = wm * 64 + mi * 16 + g * 4 + r;   // local row 0..127
      int tc = tcs[rl];
      float s = 0.f;
#pragma unroll
      for (int ni = 0; ni < 2; ++ni) {
        float logit = acc[mi][ni][r] * TEMP_INV;
        if (gcol_base + ni * 16 == tc) targ[bm * BM + rl] = logit;
        s += __expf(logit);
      }
#pragma unroll
      for (int m = 1; m < 16; m <<= 1) s += __shfl_xor(s, m, 64);
      if (cl == 0) rsum[rl][wn] = s;
    }
  }
  __syncthreads();
  if (tid < BM) {
    float s = rsum[tid][0] + rsum[tid][1] + rsum[tid][2] + rsum[tid][3];
    partial[(size_t)bn * M_DIM + bm * BM + tid] = s;
  }
}

__global__ __launch_bounds__(256) void finalize(
    const float* __restrict__ partial, const float* __restrict__ targ,
    const int* __restrict__ targets, float* __restrict__ out) {
  int r = threadIdx.x;   // 256 rows
  float s = 0.f;
  for (int j = 0; j < 128; ++j) s += partial[(size_t)j * M_DIM + r];
  int t = targets[r] - 1;
  if (t == SPECIAL) t = IGNORE_IDX;
  bool valid = (t >= 0) && (t != IGNORE_IDX);
  float nl = logf(s) - targ[r];
  float sv = valid ? nl : 0.0f;
  float cv = valid ? 1.0f : 0.0f;
#pragma unroll
  for (int m = 1; m < 64; m <<= 1) {
    sv += __shfl_xor(sv, m, 64);
    cv += __shfl_xor(cv, m, 64);
  }
  __shared__ float ss[4], cc[4];
  int wid = r >> 6, lane = r & 63;
  if (lane == 0) { ss[wid] = sv; cc[wid] = cv; }
  __syncthreads();
  if (r == 0) {
    float S = ss[0] + ss[1] + ss[2] + ss[3];
    float C = cc[0] + cc[1] + cc[2] + cc[3];
    out[0] = S / fmaxf(C, 1.0f);
  }
}

extern "C" void kernel_launch(void* const* d_in, const int* in_sizes, int n_in,
                              void* d_out, int out_size, void* d_ws, size_t ws_size,
                              hipStream_t stream) {
  const float* inputs   = (const float*)d_in[0];  // [256, 2048]
  const int*   targets  = (const int*)d_in[1];    // [256]
  const float* features = (const float*)d_in[2];  // [16384, 2048]
  float* out = (float*)d_out;

  short* Abf     = (short*)d_ws;                        // 1 MB bf16 A-image
  float* partial = (float*)((char*)d_ws + (1 << 20));   // [128][256] f32 = 128 KB
  float* targ    = partial + 128 * M_DIM;               // [256] f32

  convA<<<dim3(256), dim3(256), 0, stream>>>(inputs, Abf);
  gemm_fused<<<dim3(256), dim3(512), 0, stream>>>(Abf, features, targets, partial, targ);
  finalize<<<dim3(1), dim3(256), 0, stream>>>(partial, targ, targets, out);
}